// Round 1
// baseline (65998.755 us; speedup 1.0000x reference)
//
#include <hip/hip_runtime.h>
#include <cmath>

// Problem constants
#define Bc   64
#define Tc   2048
#define Dc   64
#define Hc   512
#define OUTc 10
#define G4H  2048          // 4*H
#define K0c  576           // D + H   (layer0 input vector)
#define K1c  1024          // H + H   (layer1 input vector)

// Persistent-kernel geometry
#define NGRP 8             // independent groups (hope: one per XCD)
#define BPG  32            // blocks per group
#define BPB  8             // batches per group
#define DPB  16            // h-dims per block (H / BPG)
#define NTHR 512           // threads per block (8 waves)
#define NKC  8             // K-chunks per matvec (one per wave)
#define KB0  (K0c / NKC)   // 72
#define KB1  (K1c / NKC)   // 128
#define PSTR 65            // padded LDS stride for partials (bank-conflict-free)

// Workspace layout (float offsets)
#define OFF_W0T 0                                   // [K0c][2048]
#define OFF_W1T (K0c * G4H)                         // [K1c][2048]
#define OFF_BS0 (OFF_W1T + K1c * G4H)               // [2048] bias sums layer0
#define OFF_BS1 (OFF_BS0 + G4H)                     // [2048]
#define OFF_HA  (OFF_BS1 + G4H)                     // [2 parity][NGRP][H*BPB]
#define OFF_HB  (OFF_HA + 2 * NGRP * Hc * BPB)
#define OFF_BAR (OFF_HB + 2 * NGRP * Hc * BPB)      // barrier counters (uint)
#define WS_FLOATS (OFF_BAR + 1024)

__global__ void prep_kernel(const float* __restrict__ Wih0, const float* __restrict__ Whh0,
                            const float* __restrict__ bih0, const float* __restrict__ bhh0,
                            const float* __restrict__ Wih1, const float* __restrict__ Whh1,
                            const float* __restrict__ bih1, const float* __restrict__ bhh1,
                            float* __restrict__ ws) {
    int idx = blockIdx.x * 256 + threadIdx.x;
    if (idx < K0c * G4H) {
        int k = idx / G4H, col = idx % G4H;
        ws[OFF_W0T + (size_t)idx] =
            (k < Dc) ? Wih0[(size_t)col * Dc + k] : Whh0[(size_t)col * Hc + (k - Dc)];
        return;
    }
    int i1 = idx - K0c * G4H;
    if (i1 < K1c * G4H) {
        int k = i1 / G4H, col = i1 % G4H;
        ws[OFF_W1T + (size_t)i1] =
            (k < Hc) ? Wih1[(size_t)col * Hc + k] : Whh1[(size_t)col * Hc + (k - Hc)];
        return;
    }
    int i2 = i1 - K1c * G4H;
    if (i2 < G4H) { ws[OFF_BS0 + i2] = bih0[i2] + bhh0[i2]; return; }
    int i3 = i2 - G4H;
    if (i3 < G4H) { ws[OFF_BS1 + i3] = bih1[i3] + bhh1[i3]; }
}

__device__ __forceinline__ float sigmf(float v) { return 1.f / (1.f + expf(-v)); }

__launch_bounds__(NTHR, 1)
__global__ void lstm_persistent(const float* __restrict__ x,
                                const float* __restrict__ Wlin,
                                const float* __restrict__ blin,
                                float* __restrict__ ws,
                                float* __restrict__ out) {
    const int g   = blockIdx.x & (NGRP - 1);  // group (XCD-local hope: round-robin dispatch)
    const int r   = blockIdx.x >> 3;          // rank within group, 0..31
    const int tid = threadIdx.x;

    float* W0T = ws + OFF_W0T;
    float* W1T = ws + OFF_W1T;
    float* bs0 = ws + OFF_BS0;
    float* bs1 = ws + OFF_BS1;
    float* hA  = ws + OFF_HA;
    float* hB  = ws + OFF_HB;
    unsigned* bar = (unsigned*)(ws + OFF_BAR);
    unsigned* cnt = bar + g * 64;             // one cache line per group
    unsigned* gen = bar + NGRP * 64 + g * 64;

    // LDS: stacked input vector [x(64) ; hA(512) ; hB(512)] x 8 batches, [k][b] layout
    __shared__ __align__(16) float inAll[(Dc + Hc + Hc) * BPB];   // 34816 B
    __shared__ float part[64 * PSTR];                             // 16640 B
    __shared__ float cst[2][DPB][BPB];                            // cell states (local!)
    __shared__ float logit_s[BPB][OUTc];

    if (tid < 2 * DPB * BPB) ((float*)cst)[tid] = 0.f;

    const int row = tid & 63;     // 0..63 : gate-row within block chunk
    const int kc  = tid >> 6;     // 0..7  : K-chunk (wave-uniform)
    const int q   = row >> 4;     // gate 0..3 (i,f,g,o)
    const int dd  = row & 15;     // dim within block
    const int col = q * Hc + r * DPB + dd;   // column in W*T / global gate row

    for (int s = 0; s <= Tc; ++s) {
        const int parA_in  = (s + 1) & 1, parA_out = s & 1;
        const int parB_in  = s & 1,       parB_out = (s + 1) & 1;

        // ---- stage inputs to LDS ----
        if (s < Tc) {
            for (int i = tid; i < BPB * Dc; i += NTHR) {
                int b = i >> 6, k = i & 63;
                inAll[k * 8 + b] = x[((size_t)(g * BPB + b) * Tc + s) * Dc + k];
            }
        }
        {
            const float* hAin = hA + ((size_t)parA_in * NGRP + g) * (Hc * BPB);
            const float* hBin = hB + ((size_t)parB_in * NGRP + g) * (Hc * BPB);
            float4* dstA = (float4*)(inAll + Dc * 8);
            float4* dstB = (float4*)(inAll + (Dc + Hc) * 8);
            for (int i = tid; i < Hc * BPB / 4; i += NTHR) dstA[i] = ((const float4*)hAin)[i];
            for (int i = tid; i < Hc * BPB / 4; i += NTHR) dstB[i] = ((const float4*)hBin)[i];
        }
        __syncthreads();

        // ---- layer 0 matvec: rows=col, K over [x ; hA] ----
        if (s < Tc) {
            float acc[8];
            #pragma unroll
            for (int b = 0; b < 8; ++b) acc[b] = 0.f;
            const float* Wp = W0T + col;
            const int k0 = kc * KB0;
            #pragma unroll 4
            for (int k = k0; k < k0 + KB0; ++k) {
                float w = Wp[(size_t)k * G4H];
                const float4 va = *(const float4*)(inAll + k * 8);
                const float4 vb = *(const float4*)(inAll + k * 8 + 4);
                acc[0] = fmaf(w, va.x, acc[0]); acc[1] = fmaf(w, va.y, acc[1]);
                acc[2] = fmaf(w, va.z, acc[2]); acc[3] = fmaf(w, va.w, acc[3]);
                acc[4] = fmaf(w, vb.x, acc[4]); acc[5] = fmaf(w, vb.y, acc[5]);
                acc[6] = fmaf(w, vb.z, acc[6]); acc[7] = fmaf(w, vb.w, acc[7]);
            }
            float* pp = part + row * PSTR + kc * 8;
            #pragma unroll
            for (int b = 0; b < 8; ++b) pp[b] = acc[b];
        }
        __syncthreads();

        // ---- layer 0 cell update (16 dims x 8 batches) ----
        if (s < Tc && tid < DPB * BPB) {
            const int d = tid >> 3, b = tid & 7;
            const int gc = r * DPB + d;
            float gate[4];
            #pragma unroll
            for (int qq = 0; qq < 4; ++qq) {
                float sum = bs0[qq * Hc + gc];
                #pragma unroll
                for (int c = 0; c < NKC; ++c) sum += part[(qq * DPB + d) * PSTR + c * 8 + b];
                gate[qq] = sum;
            }
            float iv = sigmf(gate[0]), fv = sigmf(gate[1]);
            float gv = tanhf(gate[2]), ov = sigmf(gate[3]);
            float c = fv * cst[0][d][b] + iv * gv;
            cst[0][d][b] = c;
            hA[((size_t)parA_out * NGRP + g) * (Hc * BPB) + gc * 8 + b] = ov * tanhf(c);
        }
        __syncthreads();   // part WAR protection

        // ---- layer 1 matvec: K over [hA(t) ; hB(t-1)] = inAll[64..1088) ----
        if (s >= 1) {
            float acc[8];
            #pragma unroll
            for (int b = 0; b < 8; ++b) acc[b] = 0.f;
            const float* Wp = W1T + col;
            const int k0 = kc * KB1;
            #pragma unroll 4
            for (int k = k0; k < k0 + KB1; ++k) {
                float w = Wp[(size_t)k * G4H];
                const float4 va = *(const float4*)(inAll + (Dc + k) * 8);
                const float4 vb = *(const float4*)(inAll + (Dc + k) * 8 + 4);
                acc[0] = fmaf(w, va.x, acc[0]); acc[1] = fmaf(w, va.y, acc[1]);
                acc[2] = fmaf(w, va.z, acc[2]); acc[3] = fmaf(w, va.w, acc[3]);
                acc[4] = fmaf(w, vb.x, acc[4]); acc[5] = fmaf(w, vb.y, acc[5]);
                acc[6] = fmaf(w, vb.z, acc[6]); acc[7] = fmaf(w, vb.w, acc[7]);
            }
            float* pp = part + row * PSTR + kc * 8;
            #pragma unroll
            for (int b = 0; b < 8; ++b) pp[b] = acc[b];
        }
        __syncthreads();

        // ---- layer 1 cell update ----
        if (s >= 1 && tid < DPB * BPB) {
            const int d = tid >> 3, b = tid & 7;
            const int gc = r * DPB + d;
            float gate[4];
            #pragma unroll
            for (int qq = 0; qq < 4; ++qq) {
                float sum = bs1[qq * Hc + gc];
                #pragma unroll
                for (int c = 0; c < NKC; ++c) sum += part[(qq * DPB + d) * PSTR + c * 8 + b];
                gate[qq] = sum;
            }
            float iv = sigmf(gate[0]), fv = sigmf(gate[1]);
            float gv = tanhf(gate[2]), ov = sigmf(gate[3]);
            float c = fv * cst[1][d][b] + iv * gv;
            cst[1][d][b] = c;
            hB[((size_t)parB_out * NGRP + g) * (Hc * BPB) + gc * 8 + b] = ov * tanhf(c);
        }
        __syncthreads();   // drain all global h stores (compiler waits vmcnt before barrier)

        // ---- group barrier (sense-reversing, agent scope) ----
        if (tid == 0) {
            __builtin_amdgcn_fence(__ATOMIC_RELEASE, "agent");
            unsigned gv = __hip_atomic_load(gen, __ATOMIC_RELAXED, __HIP_MEMORY_SCOPE_AGENT);
            unsigned old = __hip_atomic_fetch_add(cnt, 1u, __ATOMIC_ACQ_REL, __HIP_MEMORY_SCOPE_AGENT);
            if (old == BPG - 1) {
                __hip_atomic_store(cnt, 0u, __ATOMIC_RELAXED, __HIP_MEMORY_SCOPE_AGENT);
                __hip_atomic_store(gen, gv + 1u, __ATOMIC_RELEASE, __HIP_MEMORY_SCOPE_AGENT);
            } else {
                while (__hip_atomic_load(gen, __ATOMIC_RELAXED, __HIP_MEMORY_SCOPE_AGENT) == gv) {
                    __builtin_amdgcn_s_sleep(1);
                }
            }
            __builtin_amdgcn_fence(__ATOMIC_ACQUIRE, "agent");
        }
        __syncthreads();
    }

    // ---- final projection + log_softmax (block r==0 of each group) ----
    if (r == 0) {
        const float* hfin = hB + ((size_t)((Tc + 1) & 1) * NGRP + g) * (Hc * BPB);
        if (tid < BPB * OUTc) {
            int b = tid / OUTc, o = tid % OUTc;
            float sum = blin[o];
            for (int k = 0; k < Hc; ++k) sum = fmaf(Wlin[o * Hc + k], hfin[k * 8 + b], sum);
            logit_s[b][o] = sum;
        }
        __syncthreads();
        if (tid < BPB) {
            float m = -1e30f;
            for (int o = 0; o < OUTc; ++o) m = fmaxf(m, logit_s[tid][o]);
            float sum = 0.f;
            for (int o = 0; o < OUTc; ++o) sum += expf(logit_s[tid][o] - m);
            float lse = m + logf(sum);
            for (int o = 0; o < OUTc; ++o)
                out[(size_t)(g * BPB + tid) * OUTc + o] = logit_s[tid][o] - lse;
        }
    }
}

extern "C" void kernel_launch(void* const* d_in, const int* in_sizes, int n_in,
                              void* d_out, int out_size, void* d_ws, size_t ws_size,
                              hipStream_t stream) {
    (void)in_sizes; (void)n_in; (void)out_size; (void)ws_size;
    const float* x    = (const float*)d_in[0];
    const float* Wih0 = (const float*)d_in[1];
    const float* Whh0 = (const float*)d_in[2];
    const float* bih0 = (const float*)d_in[3];
    const float* bhh0 = (const float*)d_in[4];
    const float* Wih1 = (const float*)d_in[5];
    const float* Whh1 = (const float*)d_in[6];
    const float* bih1 = (const float*)d_in[7];
    const float* bhh1 = (const float*)d_in[8];
    const float* Wlin = (const float*)d_in[9];
    const float* blin = (const float*)d_in[10];
    float* ws  = (float*)d_ws;
    float* out = (float*)d_out;

    // zero h-state double buffers + barrier counters (d_ws is poisoned 0xAA pre-launch)
    hipMemsetAsync((char*)d_ws + (size_t)OFF_HA * 4, 0,
                   (size_t)(WS_FLOATS - OFF_HA) * 4, stream);

    // transpose weights into [k][2048] layout + bias sums
    prep_kernel<<<(K0c * G4H + K1c * G4H + 2 * G4H) / 256, 256, 0, stream>>>(
        Wih0, Whh0, bih0, bhh0, Wih1, Whh1, bih1, bhh1, ws);

    // persistent, grid-co-resident (256 blocks <= 256 CUs), group-barrier LSTM
    lstm_persistent<<<NGRP * BPG, NTHR, 0, stream>>>(x, Wlin, blin, ws, out);
}